// Round 1
// baseline (1118.400 us; speedup 1.0000x reference)
//
#include <hip/hip_runtime.h>
#include <hip/hip_bf16.h>

#define D_DIM 2048
#define F_DIM 1024
#define E_NUM 16
#define T_TOK 2048
#define TOPK 2

typedef float f32x4 __attribute__((ext_vector_type(4)));
typedef short short8 __attribute__((ext_vector_type(8)));

__device__ inline unsigned pk2bf(float a, float b) {
    __hip_bfloat162 h2 = __float22bfloat162_rn(make_float2(a, b));
    union { __hip_bfloat162 h; unsigned u; } c; c.h = h2; return c.u;
}

// ---------------- routing: 1 wave per token ----------------
__global__ __launch_bounds__(64) void k_route(const float* __restrict__ x,
                                              const float* __restrict__ wg,
                                              const float* __restrict__ bias,
                                              int* __restrict__ topk_idx,
                                              float* __restrict__ topk_w,
                                              int* __restrict__ counts) {
    int t = blockIdx.x;
    int l = threadIdx.x;
    int e = l & 15, c = l >> 4;              // expert, chunk-of-4
    const float* xr = x + (size_t)t * D_DIM + c * (D_DIM / 4);
    const float* wr = wg + (size_t)(c * (D_DIM / 4)) * E_NUM + e;
    float acc = 0.f;
#pragma unroll 4
    for (int d = 0; d < D_DIM / 4; ++d) acc += xr[d] * wr[(size_t)d * E_NUM];
    acc += __shfl_xor(acc, 16);
    acc += __shfl_xor(acc, 32);              // every lane: full logit for expert l&15
    float m = acc;
#pragma unroll
    for (int s = 1; s < 16; s <<= 1) m = fmaxf(m, __shfl_xor(m, s));
    float p = __expf(acc - m);
    float sum = p;
#pragma unroll
    for (int s = 1; s < 16; s <<= 1) sum += __shfl_xor(sum, s);
    p = p / sum + bias[e];                   // bias added AFTER softmax (ref semantics)
    // top-1 (ties -> lower index, matching jax top_k first-occurrence)
    float v1 = p; int i1 = e;
#pragma unroll
    for (int s = 1; s < 16; s <<= 1) {
        float ov = __shfl_xor(v1, s); int oi = __shfl_xor(i1, s);
        if (ov > v1 || (ov == v1 && oi < i1)) { v1 = ov; i1 = oi; }
    }
    // top-2
    float v2 = (e == i1) ? -1e30f : p; int i2 = e;
#pragma unroll
    for (int s = 1; s < 16; s <<= 1) {
        float ov = __shfl_xor(v2, s); int oi = __shfl_xor(i2, s);
        if (ov > v2 || (ov == v2 && oi < i2)) { v2 = ov; i2 = oi; }
    }
    if (l == 0) {
        float s2 = v1 + v2 + 1e-20f;
        topk_idx[2 * t] = i1; topk_idx[2 * t + 1] = i2;
        topk_w[2 * t] = v1 / s2; topk_w[2 * t + 1] = v2 / s2;
        atomicAdd(&counts[i1], 1);
        atomicAdd(&counts[i2], 1);
    }
}

__global__ void k_offsets(const int* __restrict__ counts, int* __restrict__ offsets,
                          int* __restrict__ cursors) {
    if (threadIdx.x == 0) {
        int run = 0;
        for (int e = 0; e < E_NUM; ++e) { offsets[e] = run; cursors[e] = run; run += counts[e]; }
        offsets[E_NUM] = run;
    }
}

__global__ void k_scatter(const int* __restrict__ topk_idx, const float* __restrict__ topk_w,
                          int* __restrict__ cursors, int* __restrict__ token_ids,
                          float* __restrict__ slot_w) {
    int i = blockIdx.x * blockDim.x + threadIdx.x;
    if (i >= T_TOK * TOPK) return;
    int e = topk_idx[i];
    int slot = atomicAdd(&cursors[e], 1);
    token_ids[slot] = i >> 1;
    slot_w[slot] = topk_w[i];
}

// ---------------- gate+up grouped GEMM (64x128 tile, 4 waves) ----------------
// h[slot][f] = silu(x_tok @ Wg_e)[f] * (x_tok @ Wu_e)[f], bf16
__global__ __launch_bounds__(256, 2) void k_gateup(const float* __restrict__ x,
                                                   const float* __restrict__ wg_all,
                                                   const float* __restrict__ wu_all,
                                                   const int* __restrict__ offsets,
                                                   const int* __restrict__ token_ids,
                                                   __hip_bfloat16* __restrict__ hbuf) {
    int e = blockIdx.z;
    int off = offsets[e];
    int n_e = offsets[e + 1] - off;
    int m0 = blockIdx.x * 64;
    if (m0 >= n_e) return;
    int n0 = blockIdx.y * 128;
    const float* wg = wg_all + (size_t)e * D_DIM * F_DIM;
    const float* wu = wu_all + (size_t)e * D_DIM * F_DIM;

    __shared__ unsigned short As[64 * 40];   // [64 rows][32 k] bf16, stride 40 (pad)

    int tid = threadIdx.x;
    int wid = tid >> 6, lane = tid & 63;
    int q = lane >> 4, nl = lane & 15;
    int colbase = n0 + wid * 32;             // wave covers 32 cols

    // staging map: 4 threads per row, 8 elems each
    int srow = tid >> 2, scg = (tid & 3) * 8;
    int grow = m0 + srow;
    bool valid = grow < n_e;
    const float* xrow = valid ? (x + (size_t)token_ids[off + grow] * D_DIM) : nullptr;

    f32x4 accG[4][2], accU[4][2];
#pragma unroll
    for (int ms = 0; ms < 4; ++ms)
#pragma unroll
        for (int ns = 0; ns < 2; ++ns) {
            accG[ms][ns] = (f32x4){0.f, 0.f, 0.f, 0.f};
            accU[ms][ns] = (f32x4){0.f, 0.f, 0.f, 0.f};
        }

    for (int k0 = 0; k0 < D_DIM; k0 += 32) {
        __syncthreads();                      // prev-iter LDS reads done
        // B fragments direct from global (fp32), in flight with A staging
        float bg[2][8], bu[2][8];
#pragma unroll
        for (int ns = 0; ns < 2; ++ns) {
            const float* pg = wg + (size_t)(k0 + q * 8) * F_DIM + colbase + ns * 16 + nl;
            const float* pu = wu + (size_t)(k0 + q * 8) * F_DIM + colbase + ns * 16 + nl;
#pragma unroll
            for (int i = 0; i < 8; ++i) {
                bg[ns][i] = pg[(size_t)i * F_DIM];
                bu[ns][i] = pu[(size_t)i * F_DIM];
            }
        }
        // stage A: gathered x row, fp32 -> bf16
        union { short8 s; unsigned u[4]; } av;
        if (valid) {
            float4 p0 = *(const float4*)(xrow + k0 + scg);
            float4 p1 = *(const float4*)(xrow + k0 + scg + 4);
            av.u[0] = pk2bf(p0.x, p0.y); av.u[1] = pk2bf(p0.z, p0.w);
            av.u[2] = pk2bf(p1.x, p1.y); av.u[3] = pk2bf(p1.z, p1.w);
        } else {
            av.u[0] = av.u[1] = av.u[2] = av.u[3] = 0;
        }
        *(short8*)&As[srow * 40 + scg] = av.s;
        __syncthreads();

        short8 af[4];
#pragma unroll
        for (int ms = 0; ms < 4; ++ms)
            af[ms] = *(const short8*)&As[(ms * 16 + nl) * 40 + q * 8];

        union { short8 s; unsigned u[4]; } fg[2], fu[2];
#pragma unroll
        for (int ns = 0; ns < 2; ++ns)
#pragma unroll
            for (int j = 0; j < 4; ++j) {
                fg[ns].u[j] = pk2bf(bg[ns][2 * j], bg[ns][2 * j + 1]);
                fu[ns].u[j] = pk2bf(bu[ns][2 * j], bu[ns][2 * j + 1]);
            }
#pragma unroll
        for (int ms = 0; ms < 4; ++ms)
#pragma unroll
            for (int ns = 0; ns < 2; ++ns) {
                accG[ms][ns] = __builtin_amdgcn_mfma_f32_16x16x32_bf16(af[ms], fg[ns].s, accG[ms][ns], 0, 0, 0);
                accU[ms][ns] = __builtin_amdgcn_mfma_f32_16x16x32_bf16(af[ms], fu[ns].s, accU[ms][ns], 0, 0, 0);
            }
    }

    // epilogue: silu(g)*u -> bf16 h ; D layout: col=lane&15, row=(lane>>4)*4+j
#pragma unroll
    for (int ms = 0; ms < 4; ++ms)
#pragma unroll
        for (int j = 0; j < 4; ++j) {
            int lr = ms * 16 + q * 4 + j;
            int g2 = m0 + lr;
            if (g2 < n_e) {
                size_t hbase = (size_t)(off + g2) * F_DIM;
#pragma unroll
                for (int ns = 0; ns < 2; ++ns) {
                    float g = accG[ms][ns][j];
                    float u = accU[ms][ns][j];
                    float hv = (g / (1.f + __expf(-g))) * u;
                    hbuf[hbase + colbase + ns * 16 + nl] = __float2bfloat16(hv);
                }
            }
        }
}

// ---------------- down grouped GEMM + weighted atomic combine ----------------
__global__ __launch_bounds__(256, 2) void k_down(const __hip_bfloat16* __restrict__ hbuf,
                                                 const float* __restrict__ wd_all,
                                                 const int* __restrict__ offsets,
                                                 const int* __restrict__ token_ids,
                                                 const float* __restrict__ slot_w,
                                                 float* __restrict__ y) {
    int e = blockIdx.z;
    int off = offsets[e];
    int n_e = offsets[e + 1] - off;
    int m0 = blockIdx.x * 64;
    if (m0 >= n_e) return;
    int n0 = blockIdx.y * 128;
    const float* wd = wd_all + (size_t)e * F_DIM * D_DIM;

    __shared__ unsigned short As[64 * 40];

    int tid = threadIdx.x;
    int wid = tid >> 6, lane = tid & 63;
    int q = lane >> 4, nl = lane & 15;
    int colbase = n0 + wid * 32;

    int srow = tid >> 2, scg = (tid & 3) * 8;
    int grow = m0 + srow;
    bool valid = grow < n_e;
    const unsigned short* hrow = valid ? ((const unsigned short*)hbuf + (size_t)(off + grow) * F_DIM) : nullptr;

    f32x4 acc[4][2];
#pragma unroll
    for (int ms = 0; ms < 4; ++ms)
#pragma unroll
        for (int ns = 0; ns < 2; ++ns) acc[ms][ns] = (f32x4){0.f, 0.f, 0.f, 0.f};

    for (int k0 = 0; k0 < F_DIM; k0 += 32) {
        __syncthreads();
        float bd[2][8];
#pragma unroll
        for (int ns = 0; ns < 2; ++ns) {
            const float* pd = wd + (size_t)(k0 + q * 8) * D_DIM + colbase + ns * 16 + nl;
#pragma unroll
            for (int i = 0; i < 8; ++i) bd[ns][i] = pd[(size_t)i * D_DIM];
        }
        union { short8 s; unsigned u[4]; } av;
        if (valid) {
            av.s = *(const short8*)(hrow + k0 + scg);
        } else {
            av.u[0] = av.u[1] = av.u[2] = av.u[3] = 0;
        }
        *(short8*)&As[srow * 40 + scg] = av.s;
        __syncthreads();

        short8 af[4];
#pragma unroll
        for (int ms = 0; ms < 4; ++ms)
            af[ms] = *(const short8*)&As[(ms * 16 + nl) * 40 + q * 8];

        union { short8 s; unsigned u[4]; } fd[2];
#pragma unroll
        for (int ns = 0; ns < 2; ++ns)
#pragma unroll
            for (int j = 0; j < 4; ++j)
                fd[ns].u[j] = pk2bf(bd[ns][2 * j], bd[ns][2 * j + 1]);
#pragma unroll
        for (int ms = 0; ms < 4; ++ms)
#pragma unroll
            for (int ns = 0; ns < 2; ++ns)
                acc[ms][ns] = __builtin_amdgcn_mfma_f32_16x16x32_bf16(af[ms], fd[ns].s, acc[ms][ns], 0, 0, 0);
    }

#pragma unroll
    for (int ms = 0; ms < 4; ++ms)
#pragma unroll
        for (int j = 0; j < 4; ++j) {
            int lr = ms * 16 + q * 4 + j;
            int g2 = m0 + lr;
            if (g2 < n_e) {
                float w = slot_w[off + g2];
                int t = token_ids[off + g2];
#pragma unroll
                for (int ns = 0; ns < 2; ++ns)
                    atomicAdd(&y[(size_t)t * D_DIM + colbase + ns * 16 + nl], acc[ms][ns][j] * w);
            }
        }
}

extern "C" void kernel_launch(void* const* d_in, const int* in_sizes, int n_in,
                              void* d_out, int out_size, void* d_ws, size_t ws_size,
                              hipStream_t stream) {
    const float* x      = (const float*)d_in[0];
    const float* w_gate = (const float*)d_in[1];
    const float* w_g    = (const float*)d_in[2];
    const float* w_u    = (const float*)d_in[3];
    const float* w_d    = (const float*)d_in[4];
    const float* bias   = (const float*)d_in[5];
    float* y = (float*)d_out;

    char* ws = (char*)d_ws;
    int*   counts    = (int*)(ws + 0);
    int*   offsets   = (int*)(ws + 64);
    int*   cursors   = (int*)(ws + 192);
    int*   topk_idx  = (int*)(ws + 256);
    float* topk_w    = (float*)(ws + 256 + 16384);
    int*   token_ids = (int*)(ws + 256 + 32768);
    float* slot_w    = (float*)(ws + 256 + 49152);
    __hip_bfloat16* hbuf = (__hip_bfloat16*)(ws + 66048);   // 4096*1024 bf16 = 8.39 MB

    hipMemsetAsync(ws, 0, 256, stream);
    hipMemsetAsync(d_out, 0, (size_t)out_size * sizeof(float), stream);

    k_route<<<T_TOK, 64, 0, stream>>>(x, w_gate, bias, topk_idx, topk_w, counts);
    k_offsets<<<1, 64, 0, stream>>>(counts, offsets, cursors);
    k_scatter<<<(T_TOK * TOPK + 255) / 256, 256, 0, stream>>>(topk_idx, topk_w, cursors, token_ids, slot_w);
    k_gateup<<<dim3(32, F_DIM / 128, E_NUM), 256, 0, stream>>>(x, w_g, w_u, offsets, token_ids, hbuf);
    k_down<<<dim3(32, D_DIM / 128, E_NUM), 256, 0, stream>>>(hbuf, w_d, offsets, token_ids, slot_w, y);
}

// Round 3
// 339.726 us; speedup vs baseline: 3.2921x; 3.2921x over previous
//
#include <hip/hip_runtime.h>
#include <hip/hip_bf16.h>

#define D_DIM 2048
#define F_DIM 1024
#define E_NUM 16
#define T_TOK 2048

typedef float f32x4 __attribute__((ext_vector_type(4)));
typedef short short8 __attribute__((ext_vector_type(8)));

__device__ inline unsigned pk2bf(float a, float b) {
    __hip_bfloat162 h2 = __float22bfloat162_rn(make_float2(a, b));
    union { __hip_bfloat162 h; unsigned u; } c; c.h = h2; return c.u;
}

// ---------------- routing: 1 wave per token ----------------
__global__ __launch_bounds__(64) void k_route(const float* __restrict__ x,
                                              const float* __restrict__ wg,
                                              const float* __restrict__ bias,
                                              int* __restrict__ topk_idx,
                                              float* __restrict__ topk_w,
                                              int* __restrict__ counts) {
    int t = blockIdx.x;
    int l = threadIdx.x;
    int e = l & 15, c = l >> 4;
    const float* xr = x + (size_t)t * D_DIM + c * (D_DIM / 4);
    const float* wr = wg + (size_t)(c * (D_DIM / 4)) * E_NUM + e;
    float acc = 0.f;
#pragma unroll 4
    for (int d = 0; d < D_DIM / 4; ++d) acc += xr[d] * wr[(size_t)d * E_NUM];
    acc += __shfl_xor(acc, 16);
    acc += __shfl_xor(acc, 32);
    float m = acc;
#pragma unroll
    for (int s = 1; s < 16; s <<= 1) m = fmaxf(m, __shfl_xor(m, s));
    float p = __expf(acc - m);
    float sum = p;
#pragma unroll
    for (int s = 1; s < 16; s <<= 1) sum += __shfl_xor(sum, s);
    p = p / sum + bias[e];
    float v1 = p; int i1 = e;
#pragma unroll
    for (int s = 1; s < 16; s <<= 1) {
        float ov = __shfl_xor(v1, s); int oi = __shfl_xor(i1, s);
        if (ov > v1 || (ov == v1 && oi < i1)) { v1 = ov; i1 = oi; }
    }
    float v2 = (e == i1) ? -1e30f : p; int i2 = e;
#pragma unroll
    for (int s = 1; s < 16; s <<= 1) {
        float ov = __shfl_xor(v2, s); int oi = __shfl_xor(i2, s);
        if (ov > v2 || (ov == v2 && oi < i2)) { v2 = ov; i2 = oi; }
    }
    if (l == 0) {
        float s2 = v1 + v2 + 1e-20f;
        topk_idx[2 * t] = i1; topk_idx[2 * t + 1] = i2;
        topk_w[2 * t] = v1 / s2; topk_w[2 * t + 1] = v2 / s2;
        atomicAdd(&counts[i1], 1);
        atomicAdd(&counts[i2], 1);
    }
}

__global__ void k_offsets(const int* __restrict__ counts, int* __restrict__ offsets,
                          int* __restrict__ cursors) {
    if (threadIdx.x == 0) {
        int run = 0;
        for (int e = 0; e < E_NUM; ++e) { offsets[e] = run; cursors[e] = run; run += counts[e]; }
        offsets[E_NUM] = run;
    }
}

__global__ void k_scatter(const int* __restrict__ topk_idx, const float* __restrict__ topk_w,
                          int* __restrict__ cursors, int* __restrict__ token_ids,
                          float* __restrict__ slot_w) {
    int i = blockIdx.x * blockDim.x + threadIdx.x;
    if (i >= T_TOK * 2) return;
    int e = topk_idx[i];
    int slot = atomicAdd(&cursors[e], 1);
    token_ids[slot] = i >> 1;
    slot_w[slot] = topk_w[i];
}

// ================= gate+up grouped GEMM =================
// tile 128(slots) x 64(F), BK=32, 4 waves (2x2, wave tile 64x32), double-buffered.
// A LDS: [128 rows][32 k] bf16, row stride 40 shorts (80B).
// B LDS: K-major [64 cols][32 k] bf16, col stride 40 shorts — transpose done at staging
//        (thread loads 2 k-rows x 4 cols fp32, packs k-pairs, 4x b32 writes).
// Fragment reads are plain ds_read_b128 in the round-1-verified MFMA layouts.
__global__ __launch_bounds__(256, 3) void k_gateup(const float* __restrict__ x,
                                                   const float* __restrict__ wg_all,
                                                   const float* __restrict__ wu_all,
                                                   const int* __restrict__ offsets,
                                                   const int* __restrict__ token_ids,
                                                   __hip_bfloat16* __restrict__ hbuf) {
    int e = blockIdx.z;
    int off = offsets[e];
    int n_e = offsets[e + 1] - off;
    int m0 = blockIdx.y * 128;
    if (m0 >= n_e) return;
    int n0 = blockIdx.x * 64;
    const float* wg = wg_all + (size_t)e * (D_DIM * F_DIM);
    const float* wu = wu_all + (size_t)e * (D_DIM * F_DIM);

    __shared__ unsigned short As[2][128 * 40];
    __shared__ unsigned short Bs[2][2][64 * 40];

    int tid = threadIdx.x;
    int wid = tid >> 6, lane = tid & 63;
    int q = lane >> 4, nl = lane & 15;
    int wr = wid >> 1, wc = wid & 1;

    // A staging: 2 threads/row, 16 fp32 each
    int arow = tid >> 1, acg = (tid & 1) * 16;
    int ag = m0 + arow;
    bool avalid = ag < n_e;
    const float* xrow = x + (size_t)(avalid ? token_ids[off + ag] : 0) * D_DIM;
    // B staging: thread -> k rows {bkr, bkr+1}, cols bcol..bcol+3
    int bkr = (tid >> 4) * 2;
    int bcol = (tid & 15) * 4;

    f32x4 ra[4], rg[2], ru[2];
    f32x4 accG[4][2], accU[4][2];
#pragma unroll
    for (int ms = 0; ms < 4; ++ms)
#pragma unroll
        for (int ns = 0; ns < 2; ++ns) {
            accG[ms][ns] = (f32x4){0.f, 0.f, 0.f, 0.f};
            accU[ms][ns] = (f32x4){0.f, 0.f, 0.f, 0.f};
        }

    auto loadG = [&](int k0) {
#pragma unroll
        for (int j = 0; j < 4; ++j)
            ra[j] = avalid ? *(const f32x4*)(xrow + k0 + acg + 4 * j) : (f32x4){0.f, 0.f, 0.f, 0.f};
        size_t o0 = (size_t)(k0 + bkr) * F_DIM + n0 + bcol;
        rg[0] = *(const f32x4*)(wg + o0);
        rg[1] = *(const f32x4*)(wg + o0 + F_DIM);
        ru[0] = *(const f32x4*)(wu + o0);
        ru[1] = *(const f32x4*)(wu + o0 + F_DIM);
    };
    auto writeL = [&](int b) {
        unsigned short* a = &As[b][arow * 40 + acg];
        union { short8 v; unsigned u[4]; } w0, w1;
        w0.u[0] = pk2bf(ra[0].x, ra[0].y); w0.u[1] = pk2bf(ra[0].z, ra[0].w);
        w0.u[2] = pk2bf(ra[1].x, ra[1].y); w0.u[3] = pk2bf(ra[1].z, ra[1].w);
        w1.u[0] = pk2bf(ra[2].x, ra[2].y); w1.u[1] = pk2bf(ra[2].z, ra[2].w);
        w1.u[2] = pk2bf(ra[3].x, ra[3].y); w1.u[3] = pk2bf(ra[3].z, ra[3].w);
        *(short8*)a = w0.v; *(short8*)(a + 8) = w1.v;
#pragma unroll
        for (int j = 0; j < 4; ++j) {
            // K-major: Bs[mat][col*40 + k], pack (k=bkr, k=bkr+1)
            *(unsigned*)&Bs[b][0][(bcol + j) * 40 + bkr] = pk2bf(rg[0][j], rg[1][j]);
            *(unsigned*)&Bs[b][1][(bcol + j) * 40 + bkr] = pk2bf(ru[0][j], ru[1][j]);
        }
    };
    auto compute = [&](int b) {
        short8 af[4];
#pragma unroll
        for (int ms = 0; ms < 4; ++ms)
            af[ms] = *(const short8*)&As[b][(wr * 64 + ms * 16 + nl) * 40 + q * 8];
#pragma unroll
        for (int ns = 0; ns < 2; ++ns) {
            int colb = (wc * 32 + ns * 16 + nl) * 40 + q * 8;
            short8 bg = *(const short8*)&Bs[b][0][colb];
            short8 bu = *(const short8*)&Bs[b][1][colb];
#pragma unroll
            for (int ms = 0; ms < 4; ++ms) {
                accG[ms][ns] = __builtin_amdgcn_mfma_f32_16x16x32_bf16(af[ms], bg, accG[ms][ns], 0, 0, 0);
                accU[ms][ns] = __builtin_amdgcn_mfma_f32_16x16x32_bf16(af[ms], bu, accU[ms][ns], 0, 0, 0);
            }
        }
    };

    loadG(0);
    writeL(0);
    __syncthreads();
    for (int t = 0; t < D_DIM / 32; ++t) {
        int b = t & 1;
        if (t < D_DIM / 32 - 1) loadG((t + 1) * 32);
        compute(b);
        if (t < D_DIM / 32 - 1) writeL(b ^ 1);
        __syncthreads();
    }

    // epilogue: silu(g)*u -> bf16 ; D layout: col=lane&15, row=(lane>>4)*4+j
#pragma unroll
    for (int ms = 0; ms < 4; ++ms)
#pragma unroll
        for (int j = 0; j < 4; ++j) {
            int g2 = m0 + wr * 64 + ms * 16 + q * 4 + j;
            if (g2 < n_e) {
                size_t hbase = (size_t)(off + g2) * F_DIM;
#pragma unroll
                for (int ns = 0; ns < 2; ++ns) {
                    float g = accG[ms][ns][j];
                    float u = accU[ms][ns][j];
                    float hv = (g / (1.f + __expf(-g))) * u;
                    hbuf[hbase + n0 + wc * 32 + ns * 16 + nl] = __float2bfloat16(hv);
                }
            }
        }
}

// ================= down grouped GEMM + weighted atomic combine =================
__global__ __launch_bounds__(256, 3) void k_down(const __hip_bfloat16* __restrict__ hbuf,
                                                 const float* __restrict__ wd_all,
                                                 const int* __restrict__ offsets,
                                                 const int* __restrict__ token_ids,
                                                 const float* __restrict__ slot_w,
                                                 float* __restrict__ y) {
    int e = blockIdx.z;
    int off = offsets[e];
    int n_e = offsets[e + 1] - off;
    int m0 = blockIdx.y * 128;
    if (m0 >= n_e) return;
    int n0 = blockIdx.x * 64;
    const float* wd = wd_all + (size_t)e * (F_DIM * D_DIM);

    __shared__ unsigned short As[2][128 * 40];
    __shared__ unsigned short Bs[2][64 * 40];

    int tid = threadIdx.x;
    int wid = tid >> 6, lane = tid & 63;
    int q = lane >> 4, nl = lane & 15;
    int wr = wid >> 1, wc = wid & 1;

    int arow = tid >> 1, acg = (tid & 1) * 16;
    int ag = m0 + arow;
    bool avalid = ag < n_e;
    const unsigned short* hrow = (const unsigned short*)hbuf + (size_t)(off + (avalid ? ag : 0)) * F_DIM;
    int bkr = (tid >> 4) * 2;
    int bcol = (tid & 15) * 4;

    short8 rh[2];
    f32x4 rd[2];
    f32x4 acc[4][2];
#pragma unroll
    for (int ms = 0; ms < 4; ++ms)
#pragma unroll
        for (int ns = 0; ns < 2; ++ns) acc[ms][ns] = (f32x4){0.f, 0.f, 0.f, 0.f};

    auto loadG = [&](int k0) {
        if (avalid) {
            rh[0] = *(const short8*)(hrow + k0 + acg);
            rh[1] = *(const short8*)(hrow + k0 + acg + 8);
        } else {
            rh[0] = (short8){0, 0, 0, 0, 0, 0, 0, 0};
            rh[1] = (short8){0, 0, 0, 0, 0, 0, 0, 0};
        }
        size_t o0 = (size_t)(k0 + bkr) * D_DIM + n0 + bcol;
        rd[0] = *(const f32x4*)(wd + o0);
        rd[1] = *(const f32x4*)(wd + o0 + D_DIM);
    };
    auto writeL = [&](int b) {
        unsigned short* a = &As[b][arow * 40 + acg];
        *(short8*)a = rh[0]; *(short8*)(a + 8) = rh[1];
#pragma unroll
        for (int j = 0; j < 4; ++j)
            *(unsigned*)&Bs[b][(bcol + j) * 40 + bkr] = pk2bf(rd[0][j], rd[1][j]);
    };
    auto compute = [&](int b) {
        short8 af[4];
#pragma unroll
        for (int ms = 0; ms < 4; ++ms)
            af[ms] = *(const short8*)&As[b][(wr * 64 + ms * 16 + nl) * 40 + q * 8];
#pragma unroll
        for (int ns = 0; ns < 2; ++ns) {
            short8 bd = *(const short8*)&Bs[b][(wc * 32 + ns * 16 + nl) * 40 + q * 8];
#pragma unroll
            for (int ms = 0; ms < 4; ++ms)
                acc[ms][ns] = __builtin_amdgcn_mfma_f32_16x16x32_bf16(af[ms], bd, acc[ms][ns], 0, 0, 0);
        }
    };

    loadG(0);
    writeL(0);
    __syncthreads();
    for (int t = 0; t < F_DIM / 32; ++t) {
        int b = t & 1;
        if (t < F_DIM / 32 - 1) loadG((t + 1) * 32);
        compute(b);
        if (t < F_DIM / 32 - 1) writeL(b ^ 1);
        __syncthreads();
    }

#pragma unroll
    for (int ms = 0; ms < 4; ++ms)
#pragma unroll
        for (int j = 0; j < 4; ++j) {
            int g2 = m0 + wr * 64 + ms * 16 + q * 4 + j;
            if (g2 < n_e) {
                float w = slot_w[off + g2];
                int t = token_ids[off + g2];
#pragma unroll
                for (int ns = 0; ns < 2; ++ns)
                    atomicAdd(&y[(size_t)t * D_DIM + n0 + wc * 32 + ns * 16 + nl], acc[ms][ns][j] * w);
            }
        }
}

extern "C" void kernel_launch(void* const* d_in, const int* in_sizes, int n_in,
                              void* d_out, int out_size, void* d_ws, size_t ws_size,
                              hipStream_t stream) {
    const float* x      = (const float*)d_in[0];
    const float* w_gate = (const float*)d_in[1];
    const float* w_g    = (const float*)d_in[2];
    const float* w_u    = (const float*)d_in[3];
    const float* w_d    = (const float*)d_in[4];
    const float* bias   = (const float*)d_in[5];
    float* y = (float*)d_out;

    char* ws = (char*)d_ws;
    int*   counts    = (int*)(ws + 0);
    int*   offsets   = (int*)(ws + 64);
    int*   cursors   = (int*)(ws + 192);
    int*   topk_idx  = (int*)(ws + 256);
    float* topk_w    = (float*)(ws + 256 + 16384);
    int*   token_ids = (int*)(ws + 256 + 32768);
    float* slot_w    = (float*)(ws + 256 + 49152);
    __hip_bfloat16* hbuf = (__hip_bfloat16*)(ws + 66048);   // 4096*1024 bf16

    hipMemsetAsync(ws, 0, 256, stream);
    hipMemsetAsync(d_out, 0, (size_t)out_size * sizeof(float), stream);

    k_route<<<T_TOK, 64, 0, stream>>>(x, w_gate, bias, topk_idx, topk_w, counts);
    k_offsets<<<1, 64, 0, stream>>>(counts, offsets, cursors);
    k_scatter<<<(T_TOK * 2 + 255) / 256, 256, 0, stream>>>(topk_idx, topk_w, cursors, token_ids, slot_w);
    k_gateup<<<dim3(F_DIM / 64, 16, E_NUM), 256, 0, stream>>>(x, w_g, w_u, offsets, token_ids, hbuf);
    k_down<<<dim3(D_DIM / 64, 16, E_NUM), 256, 0, stream>>>(hbuf, w_d, offsets, token_ids, slot_w, y);
}